// Round 8
// baseline (41.128 us; speedup 1.0000x reference)
//
#include <hip/hip_runtime.h>
#include <hip/hip_bf16.h>

// KANLinear as bf16 MFMA GEMM, K = i*8 + c (c: spline q=2..7 pre-scaled 1/6,
// silu, pad). Round 8: barrier-free K-loop.
//  - A (phi) staged in 4 chunks of 8 kt (64 rows x 64 i x 8 slots = 64KB LDS);
//    2 barriers per chunk (8 total, was 32). K-loop inside a chunk is pure
//    ds_read -> MFMA with register-double-buffered B: waves free-run.
//  - B straight from repacked 1MB L2-resident image, each fragment read once
//    per CU (8 waves = 8 distinct col groups, wave tile 64x32).
//  - x for next chunk prefetched into regs during current chunk's K-loop.
//  - 512 thr / 8 waves, grid 256 = 1 block/CU.

#define M_TOTAL 16384
#define IF 256
#define OF 256
#define NKT 32
#define THREADS 512

typedef __attribute__((ext_vector_type(8))) __bf16 bf16x8;
typedef __attribute__((ext_vector_type(4))) float f32x4;

// Image: 16B unit index = frag*64 + lane; frag = kt*32 + ks*16 + wn*2 + n.
// Fragment (kt,ks,wn,n), lane: col = wn*32 + n*16 + (lane&15),
// i = kt*8 + ks*4 + (lane>>4), 8 c-slots per unit.
__global__ void repack_w(const float* __restrict__ w, __bf16* __restrict__ img) {
    int g = blockIdx.x * 256 + threadIdx.x;      // 0..65535
    int lane = g & 63, frag = g >> 6;
    int n  = frag & 1;
    int wn = (frag >> 1) & 7;
    int ks = (frag >> 4) & 1;
    int kt = frag >> 5;
    int col = wn * 32 + n * 16 + (lane & 15);
    int i   = kt * 8 + ks * 4 + (lane >> 4);
    const float s6 = 1.0f / 6.0f;
    bf16x8 v;
#pragma unroll
    for (int c = 0; c < 8; ++c) {
        float f = (c < 6) ? w[(size_t)i * 2304 + col * 9 + c + 2] * s6
                : (c == 6) ? w[(size_t)i * 2304 + col * 9 + 8] : 0.0f;
        v[c] = (__bf16)f;
    }
    ((bf16x8*)img)[g] = v;
}

// one x -> A-fragment {shift-selected cubic B-spline pieces, silu, 0}
__device__ __forceinline__ bf16x8 phi_pack(float x) {
    float t  = fmaf(x, 2.5f, 5.5f);
    float fi = floorf(t);                // 5,6,7 for x in [0,1)
    float u  = (t - fi) - 3.0f;          // [-3,-2)
    float u2 = u * u, u3 = u2 * u;
    float w0 = fmaf(-1.f, u3, fmaf( 3.f, u2, fmaf(-3.f, u, 1.f)));
    float w1 = fmaf( 3.f, u3, fmaf(-6.f, u2, 4.f));
    float w2 = fmaf(-3.f, u3, fmaf( 3.f, u2, fmaf( 3.f, u, 1.f)));
    float w3 = u3;
    bool e1 = fi > 5.5f;                 // idx >= 6
    bool e2 = fi > 6.5f;                 // idx == 7
    float v0 = e1 ? 0.f : w0;
    float v1 = e2 ? 0.f : (e1 ? w0 : w1);
    float v2 = e2 ? w0  : (e1 ? w1 : w2);
    float v3 = e2 ? w1  : (e1 ? w2 : w3);
    float v4 = e2 ? w2  : (e1 ? w3 : 0.f);
    float v5 = e2 ? w3  : 0.f;
    float sl = x * __builtin_amdgcn_rcpf(1.f + __expf(-x));
    bf16x8 v;
    v[0] = (__bf16)v0; v[1] = (__bf16)v1; v[2] = (__bf16)v2; v[3] = (__bf16)v3;
    v[4] = (__bf16)v4; v[5] = (__bf16)v5; v[6] = (__bf16)sl; v[7] = (__bf16)0.f;
    return v;
}

// Slow-path gather of one B fragment directly from W (used only if ws absent).
__device__ __forceinline__ bf16x8 gather_frag(const float* __restrict__ W,
                                              int kt, int wn, int ks, int n, int lane) {
    int col = wn * 32 + n * 16 + (lane & 15);
    int i   = kt * 8 + ks * 4 + (lane >> 4);
    const float s6 = 1.0f / 6.0f;
    bf16x8 v;
#pragma unroll
    for (int c = 0; c < 8; ++c) {
        float f = (c < 6) ? W[(size_t)i * 2304 + col * 9 + c + 2] * s6
                : (c == 6) ? W[(size_t)i * 2304 + col * 9 + 8] : 0.0f;
        v[c] = (__bf16)f;
    }
    return v;
}

template <bool DIRECT_B>
__global__ __launch_bounds__(THREADS, 2)
void kan_gemm(const float* __restrict__ X, const __bf16* __restrict__ Bimg,
              const float* __restrict__ W, float* __restrict__ Y) {
    // A chunk: 64 rows x (8 kt x 8 i x 8 slots) = 64 rows x 1KB
    __shared__ alignas(16) char lds[65536];

    const int tid  = threadIdx.x;
    const int lane = tid & 63;
    const int wn   = tid >> 6;       // 0..7 col group (32 cols)
    const int l15  = lane & 15;
    const int l4   = lane >> 4;
    const int brow0 = blockIdx.x * 64;

    // phi staging: thread -> row = tid>>3, i_local = (tid&7) + 8*w, w=0..7
    const int prow = tid >> 3;           // 0..63
    const int pi   = tid & 7;            // 0..7
    const int pr7  = prow & 7;
    const float* xrow = X + (size_t)(brow0 + prow) * IF;
    char* const awb = lds + prow * 1024;

    // A-frag read swizzle: (m*16+l15)&7 == l15&7
    const int sw = l15 & 7;

    // B image base for this wave's column group
    const char* ib = (const char*)Bimg + wn * 2048 + lane * 16;
    // + kt*32768 + ks*16384 + n*1024

    f32x4 acc[4][2] = {};
    bf16x8 bcur[4], bnxt[4];    // [ks*2+n]
    float xs[8], xsn[8];

    // ---- x for chunk 0 ----
#pragma unroll
    for (int w = 0; w < 8; ++w) xs[w] = xrow[pi + 8 * w];

    // ---- B(kt=0) -> bcur ----
    if (!DIRECT_B) {
#pragma unroll
        for (int ks = 0; ks < 2; ++ks)
#pragma unroll
            for (int n = 0; n < 2; ++n)
                bcur[ks * 2 + n] = *(const bf16x8*)(ib + ks * 16384 + n * 1024);
    } else {
        bcur[0] = gather_frag(W, 0, wn, 0, 0, lane);
        bcur[1] = gather_frag(W, 0, wn, 0, 1, lane);
        bcur[2] = gather_frag(W, 0, wn, 1, 0, lane);
        bcur[3] = gather_frag(W, 0, wn, 1, 1, lane);
    }

    for (int c = 0; c < 4; ++c) {
        __syncthreads();   // previous chunk's reads complete before overwrite
#pragma unroll
        for (int w = 0; w < 8; ++w)
            *(bf16x8*)(awb + (((pi + 8 * w) ^ pr7) << 4)) = phi_pack(xs[w]);
        __syncthreads();   // chunk visible to all waves

        // prefetch x for chunk c+1 (rides over the whole 8-kt K-loop)
        if (c < 3) {
#pragma unroll
            for (int w = 0; w < 8; ++w) xsn[w] = xrow[(c + 1) * 64 + pi + 8 * w];
        }

        // ---- barrier-free 8-kt K-loop ----
#pragma unroll
        for (int ktl = 0; ktl < 8; ++ktl) {
            const int kt  = c * 8 + ktl;
            const int ktn = (kt < NKT - 1) ? kt + 1 : kt;

            // issue B(kt+1) loads first (covered by aF reads + MFMA)
            if (!DIRECT_B) {
                const char* p = ib + (size_t)ktn * 32768;
#pragma unroll
                for (int ks = 0; ks < 2; ++ks)
#pragma unroll
                    for (int n = 0; n < 2; ++n)
                        bnxt[ks * 2 + n] = *(const bf16x8*)(p + ks * 16384 + n * 1024);
            } else {
                bnxt[0] = gather_frag(W, ktn, wn, 0, 0, lane);
                bnxt[1] = gather_frag(W, ktn, wn, 0, 1, lane);
                bnxt[2] = gather_frag(W, ktn, wn, 1, 0, lane);
                bnxt[3] = gather_frag(W, ktn, wn, 1, 1, lane);
            }

            bf16x8 aF[4][2];
#pragma unroll
            for (int m = 0; m < 4; ++m)
#pragma unroll
                for (int ks = 0; ks < 2; ++ks)
                    aF[m][ks] = *(const bf16x8*)(lds + (m * 16 + l15) * 1024
                                    + (((ktl * 8 + ks * 4 + l4) ^ sw) << 4));

#pragma unroll
            for (int ks = 0; ks < 2; ++ks)
#pragma unroll
                for (int m = 0; m < 4; ++m)
#pragma unroll
                    for (int n = 0; n < 2; ++n)
                        acc[m][n] = __builtin_amdgcn_mfma_f32_16x16x32_bf16(
                            aF[m][ks], bcur[ks * 2 + n], acc[m][n], 0, 0, 0);

#pragma unroll
            for (int j = 0; j < 4; ++j) bcur[j] = bnxt[j];
        }

#pragma unroll
        for (int w = 0; w < 8; ++w) xs[w] = xsn[w];
    }

    // ---- epilogue: C/D layout col=lane&15, row=(lane>>4)*4+r ----
#pragma unroll
    for (int m = 0; m < 4; ++m)
#pragma unroll
        for (int n = 0; n < 2; ++n) {
            int col  = wn * 32 + n * 16 + l15;
            int row0 = brow0 + m * 16 + l4 * 4;
#pragma unroll
            for (int r = 0; r < 4; ++r)
                Y[(size_t)(row0 + r) * OF + col] = acc[m][n][r];
        }
}

extern "C" void kernel_launch(void* const* d_in, const int* in_sizes, int n_in,
                              void* d_out, int out_size, void* d_ws, size_t ws_size,
                              hipStream_t stream) {
    const float* X = (const float*)d_in[0];
    const float* W = (const float*)d_in[1];
    float* Y = (float*)d_out;

    size_t need = (size_t)65536 * 16;                   // 1.0 MB image
    dim3 grid(M_TOTAL / 64);                            // 256 blocks

    if (d_ws != nullptr && ws_size >= need) {
        __bf16* img = (__bf16*)d_ws;
        repack_w<<<dim3(256), dim3(256), 0, stream>>>(W, img);
        kan_gemm<false><<<grid, dim3(THREADS), 0, stream>>>(X, img, W, Y);
    } else {
        kan_gemm<true><<<grid, dim3(THREADS), 0, stream>>>(X, nullptr, W, Y);
    }
}

// Round 9
// 39.931 us; speedup vs baseline: 1.0300x; 1.0300x over previous
//
#include <hip/hip_runtime.h>
#include <hip/hip_bf16.h>

// KANLinear as bf16 MFMA GEMM, K = i*8 + c (c: spline q=2..7 pre-scaled 1/6,
// silu, pad). Round 9: round-7 traffic numbers + doubled wave parallelism.
//  - 2 independent blocks/CU (grid 512: 256 row-blocks x 2 col-halves),
//    512 thr = 8 waves = 2 rowg x 4 colg, wave tile 32x32, 4 waves/SIMD.
//    Independent barrier domains hide each other's per-kt barrier.
//  - A (phi) computed once per block, shared via 16KB double-buffered LDS
//    (XOR-swizzled, conflict-free); one barrier per kt.
//  - B straight to registers from repacked 1MB L2-resident image (rowg pairs
//    read identical addresses -> L1 line reuse; L2 traffic unchanged 256MB).

#define M_TOTAL 16384
#define IF 256
#define OF 256
#define NKT 32
#define THREADS 512

typedef __attribute__((ext_vector_type(8))) __bf16 bf16x8;
typedef __attribute__((ext_vector_type(4))) float f32x4;

// Image: 16B unit index = frag*64 + lane; frag = kt*32 + ks*16 + wn*2 + n.
// Fragment (kt,ks,wn,n), lane: col = wn*32 + n*16 + (lane&15),
// i = kt*8 + ks*4 + (lane>>4), 8 c-slots per unit.
__global__ void repack_w(const float* __restrict__ w, __bf16* __restrict__ img) {
    int g = blockIdx.x * 256 + threadIdx.x;      // 0..65535
    int lane = g & 63, frag = g >> 6;
    int n  = frag & 1;
    int wn = (frag >> 1) & 7;
    int ks = (frag >> 4) & 1;
    int kt = frag >> 5;
    int col = wn * 32 + n * 16 + (lane & 15);
    int i   = kt * 8 + ks * 4 + (lane >> 4);
    const float s6 = 1.0f / 6.0f;
    bf16x8 v;
#pragma unroll
    for (int c = 0; c < 8; ++c) {
        float f = (c < 6) ? w[(size_t)i * 2304 + col * 9 + c + 2] * s6
                : (c == 6) ? w[(size_t)i * 2304 + col * 9 + 8] : 0.0f;
        v[c] = (__bf16)f;
    }
    ((bf16x8*)img)[g] = v;
}

// one x -> A-fragment {shift-selected cubic B-spline pieces, silu, 0}
__device__ __forceinline__ bf16x8 phi_pack(float x) {
    float t  = fmaf(x, 2.5f, 5.5f);
    float fi = floorf(t);                // 5,6,7 for x in [0,1)
    float u  = (t - fi) - 3.0f;          // [-3,-2)
    float u2 = u * u, u3 = u2 * u;
    float w0 = fmaf(-1.f, u3, fmaf( 3.f, u2, fmaf(-3.f, u, 1.f)));
    float w1 = fmaf( 3.f, u3, fmaf(-6.f, u2, 4.f));
    float w2 = fmaf(-3.f, u3, fmaf( 3.f, u2, fmaf( 3.f, u, 1.f)));
    float w3 = u3;
    bool e1 = fi > 5.5f;                 // idx >= 6
    bool e2 = fi > 6.5f;                 // idx == 7
    float v0 = e1 ? 0.f : w0;
    float v1 = e2 ? 0.f : (e1 ? w0 : w1);
    float v2 = e2 ? w0  : (e1 ? w1 : w2);
    float v3 = e2 ? w1  : (e1 ? w2 : w3);
    float v4 = e2 ? w2  : (e1 ? w3 : 0.f);
    float v5 = e2 ? w3  : 0.f;
    float sl = x * __builtin_amdgcn_rcpf(1.f + __expf(-x));
    bf16x8 v;
    v[0] = (__bf16)v0; v[1] = (__bf16)v1; v[2] = (__bf16)v2; v[3] = (__bf16)v3;
    v[4] = (__bf16)v4; v[5] = (__bf16)v5; v[6] = (__bf16)sl; v[7] = (__bf16)0.f;
    return v;
}

// Slow-path gather of one B fragment directly from W (used only if ws absent).
__device__ __forceinline__ bf16x8 gather_frag(const float* __restrict__ W,
                                              int kt, int wn, int ks, int n, int lane) {
    int col = wn * 32 + n * 16 + (lane & 15);
    int i   = kt * 8 + ks * 4 + (lane >> 4);
    const float s6 = 1.0f / 6.0f;
    bf16x8 v;
#pragma unroll
    for (int c = 0; c < 8; ++c) {
        float f = (c < 6) ? W[(size_t)i * 2304 + col * 9 + c + 2] * s6
                : (c == 6) ? W[(size_t)i * 2304 + col * 9 + 8] : 0.0f;
        v[c] = (__bf16)f;
    }
    return v;
}

// One K-step: read A frags from LDS[kt&1], prefetch B(kt+1)->BN, MFMA with BC,
// phi(x[kt+1]) -> LDS[(kt+1)&1], barrier.
#define KT_BODY(KT, BC, BN)                                                   \
    {                                                                         \
        const int kt_ = (KT);                                                 \
        const bool more_ = (kt_ + 1 < NKT);                                   \
        const char* Ar_ = lds + ((kt_ & 1) << 13);                            \
        char* Aw_ = lds + (((kt_ + 1) & 1) << 13);                            \
        float xn_ = xsrc[(more_ ? kt_ + 1 : kt_) * 8];                        \
        if (more_) {                                                          \
            if (!DIRECT_B) {                                                  \
                const char* p_ = ib + (size_t)(kt_ + 1) * 32768;              \
                BN[0] = *(const bf16x8*)(p_);                                 \
                BN[1] = *(const bf16x8*)(p_ + 1024);                          \
                BN[2] = *(const bf16x8*)(p_ + 16384);                         \
                BN[3] = *(const bf16x8*)(p_ + 17408);                         \
            } else {                                                          \
                BN[0] = gather_frag(W, kt_ + 1, wn, 0, 0, lane);              \
                BN[1] = gather_frag(W, kt_ + 1, wn, 0, 1, lane);              \
                BN[2] = gather_frag(W, kt_ + 1, wn, 1, 0, lane);              \
                BN[3] = gather_frag(W, kt_ + 1, wn, 1, 1, lane);              \
            }                                                                 \
        }                                                                     \
        bf16x8 aF[2][2];                                                      \
        _Pragma("unroll") for (int m = 0; m < 2; ++m)                         \
        _Pragma("unroll") for (int ks = 0; ks < 2; ++ks)                      \
            aF[m][ks] = *(const bf16x8*)(Ar_ + (arow + m * 16) * 128          \
                            + (((ks * 4 + l4) ^ sw) << 4));                   \
        _Pragma("unroll") for (int ks = 0; ks < 2; ++ks)                      \
        _Pragma("unroll") for (int m = 0; m < 2; ++m)                         \
        _Pragma("unroll") for (int n = 0; n < 2; ++n)                         \
            acc[m][n] = __builtin_amdgcn_mfma_f32_16x16x32_bf16(              \
                aF[m][ks], BC[ks * 2 + n], acc[m][n], 0, 0, 0);               \
        if (more_) *(bf16x8*)(Aw_ + awoff) = phi_pack(xn_);                   \
        __syncthreads();                                                      \
    }

template <bool DIRECT_B>
__global__ __launch_bounds__(THREADS, 4)
void kan_gemm(const float* __restrict__ X, const __bf16* __restrict__ Bimg,
              const float* __restrict__ W, float* __restrict__ Y) {
    __shared__ alignas(16) char lds[16384];   // A dbuf: 2 x 8KB

    const int tid  = threadIdx.x;
    const int lane = tid & 63;
    const int wv   = tid >> 6;       // 0..7
    const int colg = wv & 3;         // 32-col group within this block's half
    const int rowg = wv >> 2;        // 0..1 (32 rows)
    const int l15  = lane & 15;
    const int l4   = lane >> 4;
    const int brow0 = blockIdx.x * 64;
    const int by    = blockIdx.y;    // 0..1 column half (128 cols)

    // phi staging: one phi per thread per kt (row = tid>>3, i = tid&7)
    const int prow = tid >> 3;           // 0..63
    const int pi   = tid & 7;            // 0..7
    const float* xsrc = X + (size_t)(brow0 + prow) * IF + pi;   // +8 per kt
    const int awoff = prow * 128 + ((pi ^ (prow & 7)) << 4);

    // A-frag read swizzle: (rowg*32+m*16+l15)&7 == l15&7
    const int sw   = l15 & 7;
    const int arow = rowg * 32 + l15;    // + m*16

    // B image col group 0..7 for this wave
    const int wn = by * 4 + colg;
    const char* ib = (const char*)Bimg + wn * 2048 + lane * 16;
    // + kt*32768 + ks*16384 + n*1024

    f32x4 acc[2][2] = {};
    bf16x8 bA[4], bB[4];   // [ks*2+n]

    // ---- prologue: phi(kt=0) -> LDS[0]; B(kt=0) -> bA ----
    {
        float xc = xsrc[0];
        if (!DIRECT_B) {
            bA[0] = *(const bf16x8*)(ib);
            bA[1] = *(const bf16x8*)(ib + 1024);
            bA[2] = *(const bf16x8*)(ib + 16384);
            bA[3] = *(const bf16x8*)(ib + 17408);
        } else {
            bA[0] = gather_frag(W, 0, wn, 0, 0, lane);
            bA[1] = gather_frag(W, 0, wn, 0, 1, lane);
            bA[2] = gather_frag(W, 0, wn, 1, 0, lane);
            bA[3] = gather_frag(W, 0, wn, 1, 1, lane);
        }
        *(bf16x8*)(lds + awoff) = phi_pack(xc);
    }
    __syncthreads();

    for (int kt = 0; kt < NKT; kt += 2) {
        KT_BODY(kt, bA, bB)
        KT_BODY(kt + 1, bB, bA)
    }

    // ---- epilogue: C/D layout col=lane&15, row=(lane>>4)*4+r ----
#pragma unroll
    for (int m = 0; m < 2; ++m)
#pragma unroll
        for (int n = 0; n < 2; ++n) {
            int col  = by * 128 + colg * 32 + n * 16 + l15;
            int row0 = brow0 + rowg * 32 + m * 16 + l4 * 4;
#pragma unroll
            for (int r = 0; r < 4; ++r)
                Y[(size_t)(row0 + r) * OF + col] = acc[m][n][r];
        }
}

extern "C" void kernel_launch(void* const* d_in, const int* in_sizes, int n_in,
                              void* d_out, int out_size, void* d_ws, size_t ws_size,
                              hipStream_t stream) {
    const float* X = (const float*)d_in[0];
    const float* W = (const float*)d_in[1];
    float* Y = (float*)d_out;

    size_t need = (size_t)65536 * 16;                   // 1.0 MB image
    dim3 grid(M_TOTAL / 64, 2);                         // 512 blocks, 2/CU

    if (d_ws != nullptr && ws_size >= need) {
        __bf16* img = (__bf16*)d_ws;
        repack_w<<<dim3(256), dim3(256), 0, stream>>>(W, img);
        kan_gemm<false><<<grid, dim3(THREADS), 0, stream>>>(X, img, W, Y);
    } else {
        kan_gemm<true><<<grid, dim3(THREADS), 0, stream>>>(X, nullptr, W, Y);
    }
}

// Round 10
// 29.958 us; speedup vs baseline: 1.3728x; 1.3329x over previous
//
#include <hip/hip_runtime.h>
#include <hip/hip_bf16.h>

// KANLinear as bf16 MFMA GEMM, K = i*8 + c (c: spline q=2..7 pre-scaled 1/6,
// silu, pad). Round 10: chunked A double-buffer with staging interleaved
// into the K-loop (m196 lesson: fine interleave, not phase clumping).
//  - A chunk = 4 kt (64 rows x 32 i x 8 slots = 32KB); 2 buffers = 64KB LDS.
//    During chunk c's 4-kt MFMA loop each thread computes 1 phi/kt and
//    ds_writes it into buf[c^1]. ONE barrier per chunk (9 total).
//  - x for chunk c+1's staging loaded during chunk c (use-distance ~4 kt).
//  - B register-double-buffered 1 kt ahead from repacked L2-resident image.
//  - T5 setprio(1) around MFMA cluster.
//  - 512 thr / 8 waves (8 col groups, wave tile 64x32), grid 256 = 1 block/CU.

#define M_TOTAL 16384
#define IF 256
#define OF 256
#define NKT 32
#define THREADS 512

typedef __attribute__((ext_vector_type(8))) __bf16 bf16x8;
typedef __attribute__((ext_vector_type(4))) float f32x4;

// Image: 16B unit index = frag*64 + lane; frag = kt*32 + ks*16 + wn*2 + n.
// Fragment (kt,ks,wn,n), lane: col = wn*32 + n*16 + (lane&15),
// i = kt*8 + ks*4 + (lane>>4), 8 c-slots per unit.
__global__ void repack_w(const float* __restrict__ w, __bf16* __restrict__ img) {
    int g = blockIdx.x * 256 + threadIdx.x;      // 0..65535
    int lane = g & 63, frag = g >> 6;
    int n  = frag & 1;
    int wn = (frag >> 1) & 7;
    int ks = (frag >> 4) & 1;
    int kt = frag >> 5;
    int col = wn * 32 + n * 16 + (lane & 15);
    int i   = kt * 8 + ks * 4 + (lane >> 4);
    const float s6 = 1.0f / 6.0f;
    bf16x8 v;
#pragma unroll
    for (int c = 0; c < 8; ++c) {
        float f = (c < 6) ? w[(size_t)i * 2304 + col * 9 + c + 2] * s6
                : (c == 6) ? w[(size_t)i * 2304 + col * 9 + 8] : 0.0f;
        v[c] = (__bf16)f;
    }
    ((bf16x8*)img)[g] = v;
}

// one x -> A-fragment {shift-selected cubic B-spline pieces, silu, 0}
__device__ __forceinline__ bf16x8 phi_pack(float x) {
    float t  = fmaf(x, 2.5f, 5.5f);
    float fi = floorf(t);                // 5,6,7 for x in [0,1)
    float u  = (t - fi) - 3.0f;          // [-3,-2)
    float u2 = u * u, u3 = u2 * u;
    float w0 = fmaf(-1.f, u3, fmaf( 3.f, u2, fmaf(-3.f, u, 1.f)));
    float w1 = fmaf( 3.f, u3, fmaf(-6.f, u2, 4.f));
    float w2 = fmaf(-3.f, u3, fmaf( 3.f, u2, fmaf( 3.f, u, 1.f)));
    float w3 = u3;
    bool e1 = fi > 5.5f;                 // idx >= 6
    bool e2 = fi > 6.5f;                 // idx == 7
    float v0 = e1 ? 0.f : w0;
    float v1 = e2 ? 0.f : (e1 ? w0 : w1);
    float v2 = e2 ? w0  : (e1 ? w1 : w2);
    float v3 = e2 ? w1  : (e1 ? w2 : w3);
    float v4 = e2 ? w2  : (e1 ? w3 : 0.f);
    float v5 = e2 ? w3  : 0.f;
    float sl = x * __builtin_amdgcn_rcpf(1.f + __expf(-x));
    bf16x8 v;
    v[0] = (__bf16)v0; v[1] = (__bf16)v1; v[2] = (__bf16)v2; v[3] = (__bf16)v3;
    v[4] = (__bf16)v4; v[5] = (__bf16)v5; v[6] = (__bf16)sl; v[7] = (__bf16)0.f;
    return v;
}

// Slow-path gather of one B fragment directly from W (used only if ws absent).
__device__ __forceinline__ bf16x8 gather_frag(const float* __restrict__ W,
                                              int kt, int wn, int ks, int n, int lane) {
    int col = wn * 32 + n * 16 + (lane & 15);
    int i   = kt * 8 + ks * 4 + (lane >> 4);
    const float s6 = 1.0f / 6.0f;
    bf16x8 v;
#pragma unroll
    for (int c = 0; c < 8; ++c) {
        float f = (c < 6) ? W[(size_t)i * 2304 + col * 9 + c + 2] * s6
                : (c == 6) ? W[(size_t)i * 2304 + col * 9 + 8] : 0.0f;
        v[c] = (__bf16)f;
    }
    return v;
}

template <bool DIRECT_B>
__global__ __launch_bounds__(THREADS, 2)
void kan_gemm(const float* __restrict__ X, const __bf16* __restrict__ Bimg,
              const float* __restrict__ W, float* __restrict__ Y) {
    // A dbuf: 2 x (64 rows x 512B) = 64KB. Row layout: 32 chunks of 16B,
    // chunk index XOR-swizzled with row&7.
    __shared__ alignas(16) char lds[65536];

    const int tid  = threadIdx.x;
    const int lane = tid & 63;
    const int wn   = tid >> 6;       // col group 0..7 (32 cols)
    const int l15  = lane & 15;
    const int l4   = lane >> 4;
    const int brow0 = blockIdx.x * 64;

    // phi staging: row = tid>>3, i-slot within chunk = ktl*8 + (tid&7)
    const int prow = tid >> 3;           // 0..63
    const int pi   = tid & 7;            // 0..7
    const int pr7  = prow & 7;
    const float* xrow = X + (size_t)(brow0 + prow) * IF;
    const int awbase = prow * 512;

    // A-frag read swizzle: (m*16+l15)&7 == l15&7
    const int sw = l15 & 7;

    // B image base for this wave's column group
    const char* ib = (const char*)Bimg + wn * 2048 + lane * 16;
    // + kt*32768 + ks*16384 + n*1024

    f32x4 acc[4][2] = {};
    bf16x8 breg[2][4];       // [kt parity][ks*2+n], parity always static
    float xs[4];

    // ---- prologue ----
    // x for chunk 0 staging
#pragma unroll
    for (int w = 0; w < 4; ++w) xs[w] = xrow[w * 8 + pi];
    // B(kt=0) -> breg[0]
    if (!DIRECT_B) {
        breg[0][0] = *(const bf16x8*)(ib);
        breg[0][1] = *(const bf16x8*)(ib + 1024);
        breg[0][2] = *(const bf16x8*)(ib + 16384);
        breg[0][3] = *(const bf16x8*)(ib + 17408);
    } else {
        breg[0][0] = gather_frag(W, 0, wn, 0, 0, lane);
        breg[0][1] = gather_frag(W, 0, wn, 0, 1, lane);
        breg[0][2] = gather_frag(W, 0, wn, 1, 0, lane);
        breg[0][3] = gather_frag(W, 0, wn, 1, 1, lane);
    }
    // stage chunk 0 into buf 0
#pragma unroll
    for (int w = 0; w < 4; ++w)
        *(bf16x8*)(lds + awbase + (((w * 8 + pi) ^ pr7) << 4)) = phi_pack(xs[w]);
    // x for chunk 1 staging (staged during chunk 0)
#pragma unroll
    for (int w = 0; w < 4; ++w) xs[w] = xrow[32 + w * 8 + pi];
    __syncthreads();

    for (int c = 0; c < 8; ++c) {
        const char* Ar = lds + ((c & 1) << 15);
        char* Aw = lds + (((c + 1) & 1) << 15);

#pragma unroll
        for (int ktl = 0; ktl < 4; ++ktl) {
            const int kt  = c * 4 + ktl;
            const int ktn = (kt < NKT - 1) ? kt + 1 : kt;
            // ---- B(kt+1) prefetch into breg[(ktl+1)&1] (static parity) ----
            if (!DIRECT_B) {
                const char* p = ib + (size_t)ktn * 32768;
                breg[(ktl + 1) & 1][0] = *(const bf16x8*)(p);
                breg[(ktl + 1) & 1][1] = *(const bf16x8*)(p + 1024);
                breg[(ktl + 1) & 1][2] = *(const bf16x8*)(p + 16384);
                breg[(ktl + 1) & 1][3] = *(const bf16x8*)(p + 17408);
            } else {
                breg[(ktl + 1) & 1][0] = gather_frag(W, ktn, wn, 0, 0, lane);
                breg[(ktl + 1) & 1][1] = gather_frag(W, ktn, wn, 0, 1, lane);
                breg[(ktl + 1) & 1][2] = gather_frag(W, ktn, wn, 1, 0, lane);
                breg[(ktl + 1) & 1][3] = gather_frag(W, ktn, wn, 1, 1, lane);
            }

            // ---- A-fragment reads for this kt ----
            bf16x8 aF[4][2];
#pragma unroll
            for (int m = 0; m < 4; ++m)
#pragma unroll
                for (int ks = 0; ks < 2; ++ks)
                    aF[m][ks] = *(const bf16x8*)(Ar + (m * 16 + l15) * 512
                                    + (((ktl * 8 + ks * 4 + l4) ^ sw) << 4));

            // ---- MFMA cluster ----
            __builtin_amdgcn_s_setprio(1);
#pragma unroll
            for (int ks = 0; ks < 2; ++ks)
#pragma unroll
                for (int m = 0; m < 4; ++m)
#pragma unroll
                    for (int n = 0; n < 2; ++n)
                        acc[m][n] = __builtin_amdgcn_mfma_f32_16x16x32_bf16(
                            aF[m][ks], breg[ktl & 1][ks * 2 + n], acc[m][n], 0, 0, 0);
            __builtin_amdgcn_s_setprio(0);

            // ---- interleaved staging of chunk c+1 (1 phi per kt) ----
            if (c < 7) {
                *(bf16x8*)(Aw + awbase + (((ktl * 8 + pi) ^ pr7) << 4))
                    = phi_pack(xs[ktl]);
                // refill xs[ktl] with x for chunk c+2's staging
                if (c < 6) xs[ktl] = xrow[(c + 2) * 32 + ktl * 8 + pi];
            }
        }
        __syncthreads();
    }

    // ---- epilogue: C/D layout col=lane&15, row=(lane>>4)*4+r ----
#pragma unroll
    for (int m = 0; m < 4; ++m)
#pragma unroll
        for (int n = 0; n < 2; ++n) {
            int col  = wn * 32 + n * 16 + l15;
            int row0 = brow0 + m * 16 + l4 * 4;
#pragma unroll
            for (int r = 0; r < 4; ++r)
                Y[(size_t)(row0 + r) * OF + col] = acc[m][n][r];
        }
}

extern "C" void kernel_launch(void* const* d_in, const int* in_sizes, int n_in,
                              void* d_out, int out_size, void* d_ws, size_t ws_size,
                              hipStream_t stream) {
    const float* X = (const float*)d_in[0];
    const float* W = (const float*)d_in[1];
    float* Y = (float*)d_out;

    size_t need = (size_t)65536 * 16;                   // 1.0 MB image
    dim3 grid(M_TOTAL / 64);                            // 256 blocks, 1/CU

    if (d_ws != nullptr && ws_size >= need) {
        __bf16* img = (__bf16*)d_ws;
        repack_w<<<dim3(256), dim3(256), 0, stream>>>(W, img);
        kan_gemm<false><<<grid, dim3(THREADS), 0, stream>>>(X, img, W, Y);
    } else {
        kan_gemm<true><<<grid, dim3(THREADS), 0, stream>>>(X, nullptr, W, Y);
    }
}